// Round 6
// baseline (313.268 us; speedup 1.0000x reference)
//
#include <hip/hip_runtime.h>
#include <stdint.h>

// VectorQuantizer: z [32768,64], codebook [1024,64] (dtype sniffed bf16/f32).
// d_out FLOAT32: z_q_st [2097152] ++ loss [1] ++ indices [32768].
// Bit-exact replication of the reference f32 arithmetic (numpy pairwise sums,
// sequential non-fused dot, f32 final adds, first-index argmin).
//
// R9 vs R8 (262us, VALUBusy 31%): R8 ran at 3.1x its VALU floor, latency-bound
// because zf[64] ate 64 of 80 VGPRs and the compiler strip-mined code loads
// into serial load-wait-compute chunks. Now the code scan is explicitly
// software-pipelined with TWO named register buffers (compute code i from A
// while B prefetches i+1), costing ~64 VGPRs. Arithmetic order unchanged.
#define N_ROWS 32768
#define DIM 64
#define K_CODES 1024
#define ROWS_PER_BLOCK 32
#define PARTS 8
#define CODES_PER_THREAD (K_CODES / PARTS)    // 128
#define NBLOCKS (N_ROWS / ROWS_PER_BLOCK)     // 1024
#define N_ELEMS (N_ROWS * DIM)                // 2097152

// workspace layout (bytes):
// [0,4096)      float cc[1024]
// [4096,4100)   int flags  (bit0: z is bf16, bit1: cb is bf16)
// [8192,8192+NBLOCKS*8)  double partials[NBLOCKS]

__device__ __forceinline__ float bfbits(uint32_t b) { return __uint_as_float(b << 16); }
__device__ __forceinline__ float bf_lo(uint32_t u) { return __uint_as_float(u << 16); }
__device__ __forceinline__ float bf_hi(uint32_t u) { return __uint_as_float(u & 0xFFFF0000u); }

// round f32 -> nearest bf16 value, returned AS f32 (RNE; finite inputs)
__device__ __forceinline__ float round_bf16(float f) {
  uint32_t u = __float_as_uint(f);
  uint32_t r = ((u + 0x7FFFu + ((u >> 16) & 1u)) >> 16) << 16;
  return __uint_as_float(r);
}

// numpy pairwise_sum for n=64 (8 accumulators, 8 rounds, numpy's combine tree).
template <typename F>
__device__ __forceinline__ float np_sum64(F get) {
  float r0 = get(0), r1 = get(1), r2 = get(2), r3 = get(3);
  float r4 = get(4), r5 = get(5), r6 = get(6), r7 = get(7);
  for (int i = 8; i < 64; i += 8) {
    r0 = __fadd_rn(r0, get(i + 0)); r1 = __fadd_rn(r1, get(i + 1));
    r2 = __fadd_rn(r2, get(i + 2)); r3 = __fadd_rn(r3, get(i + 3));
    r4 = __fadd_rn(r4, get(i + 4)); r5 = __fadd_rn(r5, get(i + 5));
    r6 = __fadd_rn(r6, get(i + 6)); r7 = __fadd_rn(r7, get(i + 7));
  }
  return __fadd_rn(__fadd_rn(__fadd_rn(r0, r1), __fadd_rn(r2, r3)),
                   __fadd_rn(__fadd_rn(r4, r5), __fadd_rn(r6, r7)));
}

// Precompute: dtype sniff (block 0 writes flags) + cc_k = np.sum(c*c) per code.
__global__ __launch_bounds__(256) void vq_prep_kernel(
    const void* __restrict__ z, const void* __restrict__ cb,
    float* __restrict__ cc_out, int* __restrict__ flags) {
  const int tid = threadIdx.x;
  __shared__ int s_cnt[2];
  if (tid < 2) s_cnt[tid] = 0;
  __syncthreads();
  if (tid < 128) {
    uint32_t wc = ((const uint32_t*)cb)[(size_t)tid * 255];
    float vc = fabsf(bfbits(wc & 0xFFFFu));
    if (vc == 0.0f || (vc > 5.9e-8f && vc < 32.0f)) atomicAdd(&s_cnt[1], 1);
    if (blockIdx.x == 0) {
      uint32_t wz = ((const uint32_t*)z)[(size_t)tid * 8191];
      float vz = fabsf(bfbits(wz & 0xFFFFu));
      if (vz == 0.0f || (vz > 5.9e-8f && vz < 32.0f)) atomicAdd(&s_cnt[0], 1);
    }
  }
  __syncthreads();
  const bool cb_bf16 = s_cnt[1] >= 96;
  if (blockIdx.x == 0 && tid == 0)
    flags[0] = (s_cnt[0] >= 96 ? 1 : 0) | (cb_bf16 ? 2 : 0);

  const int kk = blockIdx.x * 256 + tid;
  float v;
  if (cb_bf16) {
    const uint16_t* cp = (const uint16_t*)cb + (size_t)kk * DIM;
    v = np_sum64([&](int d) { float c = bfbits((uint32_t)cp[d]);
                              return __fmul_rn(c, c); });
  } else {
    const float* cp = (const float*)cb + (size_t)kk * DIM;
    v = np_sum64([&](int d) { return __fmul_rn(cp[d], cp[d]); });
  }
  cc_out[kk] = v;
}

// Thread = (row r = tid&31, part = tid>>5); part p scans codes 32g+4p+j
// (g=0..31, j=0..3) ascending. idx in [0,128) -> k = 32*(idx>>2)+4p+(idx&3).
__device__ __forceinline__ int kidx(int idx, int part) {
  return ((idx >> 2) << 5) + (part << 2) + (idx & 3);
}

__global__ __launch_bounds__(256) void vq_kernel(
    const void* __restrict__ z, const void* __restrict__ cb,
    const float* __restrict__ cc_in, const int* __restrict__ flags,
    float* __restrict__ out, double* __restrict__ partials) {
  const int tid = threadIdx.x;
  const int fl = flags[0];
  const bool z_bf16  = (fl & 1) != 0;
  const bool cb_bf16 = (fl & 2) != 0;

  __shared__ float s_cc[K_CODES];                 // 4 KB
  __shared__ float s_best[256];
  __shared__ int s_k[256];
  __shared__ int s_win[ROWS_PER_BLOCK];
  __shared__ double s_loss[ROWS_PER_BLOCK];

  #pragma unroll
  for (int kk = tid; kk < K_CODES; kk += 256) s_cc[kk] = cc_in[kk];

  const int r = tid & (ROWS_PER_BLOCK - 1);
  const int part = tid >> 5;
  const size_t row = (size_t)blockIdx.x * ROWS_PER_BLOCK + r;

  // Load z row as exact f32 values (vectorized).
  float zf[DIM];
  if (z_bf16) {
    const uint4* p = (const uint4*)((const uint16_t*)z + row * DIM);
    #pragma unroll
    for (int j = 0; j < 8; ++j) {
      uint4 u = p[j];
      zf[j * 8 + 0] = bf_lo(u.x); zf[j * 8 + 1] = bf_hi(u.x);
      zf[j * 8 + 2] = bf_lo(u.y); zf[j * 8 + 3] = bf_hi(u.y);
      zf[j * 8 + 4] = bf_lo(u.z); zf[j * 8 + 5] = bf_hi(u.z);
      zf[j * 8 + 6] = bf_lo(u.w); zf[j * 8 + 7] = bf_hi(u.w);
    }
  } else {
    const float4* p = (const float4*)((const float*)z + row * DIM);
    #pragma unroll
    for (int j = 0; j < 16; ++j) {
      float4 v = p[j];
      zf[j * 4 + 0] = v.x; zf[j * 4 + 1] = v.y;
      zf[j * 4 + 2] = v.z; zf[j * 4 + 3] = v.w;
    }
  }
  // zz = np.sum(z*z, axis=1) in f32, numpy pairwise order.
  const float zz = np_sum64([&](int d) { return __fmul_rn(zf[d], zf[d]); });

  __syncthreads();  // s_cc ready

  // Scan: d2 = fl(fl(zz + cc_k) - fl(2*g)), g = sequential f32 dot ascending d
  // (einsum inner loop, non-fused). Per-thread k ascending, strict < (np ties).
  float best = 3.4e38f;
  int bk = 0;

  if (cb_bf16) {
    const uint4* cb4 = (const uint4*)cb;      // 8 uint4 per code
    uint4 bufA[8], bufB[8];
    {
      const uint4* p0 = cb4 + (size_t)kidx(0, part) * 8;
      const uint4* p1 = cb4 + (size_t)kidx(1, part) * 8;
      #pragma unroll
      for (int j = 0; j < 8; ++j) bufA[j] = p0[j];
      #pragma unroll
      for (int j = 0; j < 8; ++j) bufB[j] = p1[j];
    }
    for (int idx = 0; idx < CODES_PER_THREAD; idx += 2) {
      // ---- compute code idx from bufA ----
      {
        float g = 0.0f;
        #pragma unroll
        for (int j = 0; j < 8; ++j) {
          uint4 u = bufA[j];
          const int d0 = j * 8;
          g = __fadd_rn(g, __fmul_rn(zf[d0 + 0], bf_lo(u.x)));
          g = __fadd_rn(g, __fmul_rn(zf[d0 + 1], bf_hi(u.x)));
          g = __fadd_rn(g, __fmul_rn(zf[d0 + 2], bf_lo(u.y)));
          g = __fadd_rn(g, __fmul_rn(zf[d0 + 3], bf_hi(u.y)));
          g = __fadd_rn(g, __fmul_rn(zf[d0 + 4], bf_lo(u.z)));
          g = __fadd_rn(g, __fmul_rn(zf[d0 + 5], bf_hi(u.z)));
          g = __fadd_rn(g, __fmul_rn(zf[d0 + 6], bf_lo(u.w)));
          g = __fadd_rn(g, __fmul_rn(zf[d0 + 7], bf_hi(u.w)));
        }
        const int k = kidx(idx, part);
        float e = __fsub_rn(__fadd_rn(zz, s_cc[k]), __fmul_rn(2.0f, g));
        if (e < best) { best = e; bk = k; }
      }
      // ---- prefetch code idx+2 into bufA (clamped; reload is harmless) ----
      {
        int n = idx + 2; if (n >= CODES_PER_THREAD) n = CODES_PER_THREAD - 1;
        const uint4* p = cb4 + (size_t)kidx(n, part) * 8;
        #pragma unroll
        for (int j = 0; j < 8; ++j) bufA[j] = p[j];
      }
      // ---- compute code idx+1 from bufB ----
      {
        float g = 0.0f;
        #pragma unroll
        for (int j = 0; j < 8; ++j) {
          uint4 u = bufB[j];
          const int d0 = j * 8;
          g = __fadd_rn(g, __fmul_rn(zf[d0 + 0], bf_lo(u.x)));
          g = __fadd_rn(g, __fmul_rn(zf[d0 + 1], bf_hi(u.x)));
          g = __fadd_rn(g, __fmul_rn(zf[d0 + 2], bf_lo(u.y)));
          g = __fadd_rn(g, __fmul_rn(zf[d0 + 3], bf_hi(u.y)));
          g = __fadd_rn(g, __fmul_rn(zf[d0 + 4], bf_lo(u.z)));
          g = __fadd_rn(g, __fmul_rn(zf[d0 + 5], bf_hi(u.z)));
          g = __fadd_rn(g, __fmul_rn(zf[d0 + 6], bf_lo(u.w)));
          g = __fadd_rn(g, __fmul_rn(zf[d0 + 7], bf_hi(u.w)));
        }
        const int k = kidx(idx + 1, part);
        float e = __fsub_rn(__fadd_rn(zz, s_cc[k]), __fmul_rn(2.0f, g));
        if (e < best) { best = e; bk = k; }
      }
      // ---- prefetch code idx+3 into bufB (clamped) ----
      {
        int n = idx + 3; if (n >= CODES_PER_THREAD) n = CODES_PER_THREAD - 1;
        const uint4* p = cb4 + (size_t)kidx(n, part) * 8;
        #pragma unroll
        for (int j = 0; j < 8; ++j) bufB[j] = p[j];
      }
    }
  } else {
    // f32: one code = 16 float4. Pipeline at half-code granularity: bufA holds
    // dims 0..31, bufB dims 32..63 of the current code; g carries across the
    // two halves (sequential chain preserved).
    const float4* cbf = (const float4*)cb;    // 16 float4 per code
    float4 bufA[8], bufB[8];
    {
      const float4* p = cbf + (size_t)kidx(0, part) * 16;
      #pragma unroll
      for (int j = 0; j < 8; ++j) bufA[j] = p[j];
      #pragma unroll
      for (int j = 0; j < 8; ++j) bufB[j] = p[j + 8];
    }
    for (int idx = 0; idx < CODES_PER_THREAD; ++idx) {
      int n = idx + 1; if (n >= CODES_PER_THREAD) n = CODES_PER_THREAD - 1;
      const float4* np_ = cbf + (size_t)kidx(n, part) * 16;
      float g = 0.0f;
      // first half (dims 0..31) from bufA
      #pragma unroll
      for (int j = 0; j < 8; ++j) {
        float4 a = bufA[j];
        const int d0 = j * 4;
        g = __fadd_rn(g, __fmul_rn(zf[d0 + 0], a.x));
        g = __fadd_rn(g, __fmul_rn(zf[d0 + 1], a.y));
        g = __fadd_rn(g, __fmul_rn(zf[d0 + 2], a.z));
        g = __fadd_rn(g, __fmul_rn(zf[d0 + 3], a.w));
      }
      // prefetch next code's first half into bufA
      #pragma unroll
      for (int j = 0; j < 8; ++j) bufA[j] = np_[j];
      // second half (dims 32..63) from bufB
      #pragma unroll
      for (int j = 0; j < 8; ++j) {
        float4 b = bufB[j];
        const int d0 = 32 + j * 4;
        g = __fadd_rn(g, __fmul_rn(zf[d0 + 0], b.x));
        g = __fadd_rn(g, __fmul_rn(zf[d0 + 1], b.y));
        g = __fadd_rn(g, __fmul_rn(zf[d0 + 2], b.z));
        g = __fadd_rn(g, __fmul_rn(zf[d0 + 3], b.w));
      }
      // prefetch next code's second half into bufB
      #pragma unroll
      for (int j = 0; j < 8; ++j) bufB[j] = np_[j + 8];
      const int k = kidx(idx, part);
      float e = __fsub_rn(__fadd_rn(zz, s_cc[k]), __fmul_rn(2.0f, g));
      if (e < best) { best = e; bk = k; }
    }
  }

  s_best[tid] = best;
  s_k[tid] = bk;
  __syncthreads();

  if (tid < ROWS_PER_BLOCK) {
    // Parts interleave k -> merge with lexicographic (d2, k): exactly the
    // global first-index (numpy) argmin.
    float b = 3.4e38f;
    int bbk = 0x7FFFFFFF;
    for (int p = 0; p < PARTS; ++p) {
      float v = s_best[p * ROWS_PER_BLOCK + tid];
      int vk = s_k[p * ROWS_PER_BLOCK + tid];
      if (v < b || (v == b && vk < bbk)) { b = v; bbk = vk; }
    }
    s_win[tid] = bbk;
    // Exact squared distance of the winner (fp64) — thread tid owns row tid's zf
    // (tid < 32 => r == tid, part == 0).
    double acc = 0.0;
    if (cb_bf16) {
      const uint16_t* cp = (const uint16_t*)cb + (size_t)bbk * DIM;
      for (int d = 0; d < DIM; ++d) {
        double df = (double)zf[d] - (double)bfbits((uint32_t)cp[d]);
        acc = fma(df, df, acc);
      }
    } else {
      const float* cp = (const float*)cb + (size_t)bbk * DIM;
      for (int d = 0; d < DIM; ++d) {
        double df = (double)zf[d] - (double)cp[d];
        acc = fma(df, df, acc);
      }
    }
    s_loss[tid] = acc;
    const size_t myrow = (size_t)blockIdx.x * ROWS_PER_BLOCK + tid;
    out[(size_t)N_ELEMS + 1 + myrow] = round_bf16((float)bbk);
  }
  __syncthreads();

  // z_q write: 32 rows x 64 dims = 2048 floats, 256 threads x 8, coalesced.
  const size_t base = (size_t)blockIdx.x * ROWS_PER_BLOCK * DIM;
  #pragma unroll
  for (int j = 0; j < 8; ++j) {
    int idx = tid + 256 * j;
    int rr = idx >> 6, dd = idx & 63;
    int w = s_win[rr];
    float v;
    if (cb_bf16) v = bfbits((uint32_t)((const uint16_t*)cb)[(size_t)w * DIM + dd]);
    else         v = round_bf16(((const float*)cb)[(size_t)w * DIM + dd]);
    out[base + idx] = v;
  }

  if (tid == 0) {
    double s = 0.0;
    for (int i = 0; i < ROWS_PER_BLOCK; ++i) s += s_loss[i];
    partials[blockIdx.x] = s;
  }
}

__global__ __launch_bounds__(256) void vq_loss_kernel(
    const double* __restrict__ partials, float* __restrict__ out) {
  __shared__ double sh[256];
  const int tid = threadIdx.x;
  double s = 0.0;
  for (int i = tid; i < NBLOCKS; i += 256) s += partials[i];
  sh[tid] = s;
  __syncthreads();
  if (tid == 0) {
    double t = 0.0;
    for (int i = 0; i < 256; ++i) t += sh[i];
    out[N_ELEMS] = round_bf16((float)(1.25 * t / (double)N_ELEMS));
  }
}

extern "C" void kernel_launch(void* const* d_in, const int* in_sizes, int n_in,
                              void* d_out, int out_size, void* d_ws, size_t ws_size,
                              hipStream_t stream) {
  const void* z  = d_in[0];
  const void* cb = d_in[1];
  float* out = (float*)d_out;
  uint8_t* ws = (uint8_t*)d_ws;
  float* cc = (float*)ws;
  int* flags = (int*)(ws + 4096);
  double* partials = (double*)(ws + 8192);

  vq_prep_kernel<<<K_CODES / 256, 256, 0, stream>>>(z, cb, cc, flags);
  vq_kernel<<<NBLOCKS, 256, 0, stream>>>(z, cb, cc, flags, out, partials);
  vq_loss_kernel<<<1, 256, 0, stream>>>(partials, out);
}